// Round 5
// baseline (540.894 us; speedup 1.0000x reference)
//
#include <hip/hip_runtime.h>

// ---------------------------------------------------------------------------
// LUNA fused pipeline for MI355X / gfx950.  B=16, S=4096, P=64, QKV=512, H=8.
// R5: 2-phase (T3-minimum) GEMMs with double-buffered LDS — loads for tile
//     t+1 issued BEFORE compute of tile t, so the barrier drain finds them
//     already ~400cyc old.  A fp32 reg-staged (T14) + ds_write bf16; B via
//     global_load_lds.  R4 showed 63% stall cycles in the 1-phase structure.
// ---------------------------------------------------------------------------

typedef __bf16 bf16x8 __attribute__((ext_vector_type(8)));
typedef float f32x4 __attribute__((ext_vector_type(4)));
typedef unsigned short u16x8 __attribute__((ext_vector_type(8)));
typedef unsigned short u16x4 __attribute__((ext_vector_type(4)));

#define MFMA16(a, b, c) __builtin_amdgcn_mfma_f32_16x16x32_bf16((a), (b), (c), 0, 0, 0)

__device__ __forceinline__ unsigned short f2bf_bits(float f) {
  unsigned int u = __float_as_uint(f);
  u += 0x7fffu + ((u >> 16) & 1u);  // RTNE (finite inputs)
  return (unsigned short)(u >> 16);
}

__device__ __forceinline__ void gload16(const void* g, void* l) {
  __builtin_amdgcn_global_load_lds(
      (const __attribute__((address_space(1))) void*)g,
      (__attribute__((address_space(3))) void*)l, 16, 0, 0);
}

// ---------------------------------------------------------------------------
// prep: z 0..7 -> transpose+convert W_z into bf16 W^T; z==8 -> combined biases.
// ---------------------------------------------------------------------------
struct Ptr8 { const float* p[8]; };

__global__ __launch_bounds__(256) void prep_kernel(
    Ptr8 srcs, unsigned short* __restrict__ WT,
    const float* bi, const float* bip, const float* bic,
    const float* Wq, const float* Wpq, const float* Wpk, const float* Wpv,
    const float* bq, const float* bpq, const float* bpk, const float* bpv,
    float* __restrict__ bias_out) {
  const int t = threadIdx.x;
  if (blockIdx.z < 8) {
    const float* __restrict__ W = srcs.p[blockIdx.z];
    unsigned short* __restrict__ O = WT + (size_t)blockIdx.z * 262144;
    __shared__ float tile[32][33];
    const int tr = blockIdx.x * 32, tc = blockIdx.y * 32;
    {
      const int r = t >> 3, c4 = (t & 7) * 4;
      const float4 v = *reinterpret_cast<const float4*>(&W[(size_t)(tr + r) * 512 + tc + c4]);
      tile[r][c4 + 0] = v.x; tile[r][c4 + 1] = v.y; tile[r][c4 + 2] = v.z; tile[r][c4 + 3] = v.w;
    }
    __syncthreads();
    {
      const int n = t >> 3, k4 = (t & 7) * 4;
      u16x4 o;
#pragma unroll
      for (int j = 0; j < 4; j++) o[j] = f2bf_bits(tile[k4 + j][n]);
      *reinterpret_cast<u16x4*>(&O[(size_t)(tc + n) * 512 + tr + k4]) = o;
    }
  } else {
    const int idx = blockIdx.y * 16 + blockIdx.x;
    if (idx >= 8) return;
    const int y = idx >> 1;
    const float* bin  = (y == 0) ? bi : (y == 1) ? bip : bic;
    const float* W    = (y == 0) ? Wq : (y == 1) ? Wpq : (y == 2) ? Wpk : Wpv;
    const float* bout = (y == 0) ? bq : (y == 1) ? bpq : (y == 2) ? bpk : bpv;
    const float scale = (y < 2) ? 0.125f : 1.0f;
    const int n = (idx & 1) * 256 + t;
    float s = 0.f;
    for (int k = 0; k < 512; k++) s += bin[k] * W[(size_t)k * 512 + n];
    bias_out[y * 512 + n] = (s + bout[n]) * scale;
  }
}

// ---------------------------------------------------------------------------
// Batched weight-combine: out_z^T = scale_z * (A_z @ WT_z^T), z in 0..3.
// ---------------------------------------------------------------------------
__global__ __launch_bounds__(256) void gemm_wcomb(
    const float* __restrict__ Wi, const float* __restrict__ Wip,
    const float* __restrict__ Wic, const unsigned short* __restrict__ WTbase,
    unsigned short* __restrict__ outbase) {
  const int z = blockIdx.z;
  const float* __restrict__ A = (z == 0) ? Wi : (z == 1) ? Wip : Wic;
  const unsigned short* __restrict__ BT = WTbase + (size_t)z * 262144;
  unsigned short* __restrict__ out = outbase + (size_t)z * 262144;
  const float scale = (z < 2) ? 0.125f : 1.0f;

  __shared__ __align__(16) unsigned short As[128 * 72];
  __shared__ __align__(16) unsigned short Bs[128 * 72];
  const int t = threadIdx.x;
  const int w = t >> 6, l = t & 63, li = l & 15, lg = l >> 4;
  const int wm = w >> 1, wn = w & 1;
  const int m0 = blockIdx.x * 128, n0 = blockIdx.y * 128;

  f32x4 acc[4][4] = {};

  for (int kt = 0; kt < 512; kt += 64) {
#pragma unroll
    for (int i = 0; i < 8; i++) {
      const int row = i * 16 + (t >> 4), k = (t & 15) * 4;
      const float4 v = *reinterpret_cast<const float4*>(&A[(size_t)(m0 + row) * 512 + kt + k]);
      u16x4 o;
      o[0] = f2bf_bits(v.x); o[1] = f2bf_bits(v.y);
      o[2] = f2bf_bits(v.z); o[3] = f2bf_bits(v.w);
      *reinterpret_cast<u16x4*>(&As[row * 72 + k]) = o;
    }
#pragma unroll
    for (int i = 0; i < 4; i++) {
      const int row = i * 32 + (t >> 3), k = (t & 7) * 8;
      const u16x8 v = *reinterpret_cast<const u16x8*>(&BT[(size_t)(n0 + row) * 512 + kt + k]);
      *reinterpret_cast<u16x8*>(&Bs[row * 72 + k]) = v;
    }
    __syncthreads();
#pragma unroll
    for (int kk = 0; kk < 2; kk++) {
      bf16x8 a[4], b[4];
#pragma unroll
      for (int mf = 0; mf < 4; mf++)
        a[mf] = *reinterpret_cast<const bf16x8*>(&As[(wm * 64 + mf * 16 + li) * 72 + kk * 32 + lg * 8]);
#pragma unroll
      for (int nf = 0; nf < 4; nf++)
        b[nf] = *reinterpret_cast<const bf16x8*>(&Bs[(wn * 64 + nf * 16 + li) * 72 + kk * 32 + lg * 8]);
#pragma unroll
      for (int mf = 0; mf < 4; mf++)
#pragma unroll
        for (int nf = 0; nf < 4; nf++)
          acc[mf][nf] = MFMA16(a[mf], b[nf], acc[mf][nf]);
    }
    __syncthreads();
  }
  const int lg4 = lg * 4;
#pragma unroll
  for (int nf = 0; nf < 4; nf++) {
    const int col = n0 + wn * 64 + nf * 16 + li;
#pragma unroll
    for (int mf = 0; mf < 4; mf++) {
      const int row = m0 + wm * 64 + mf * 16 + lg4;
#pragma unroll
      for (int r = 0; r < 4; r++)
        out[(size_t)col * 512 + row + r] = f2bf_bits(acc[mf][nf][r] * scale);
    }
  }
}

// ---------------------------------------------------------------------------
// gemm2ph_f32a: C[MxN] = bf16(A_fp32) @ BT^T + bias, bf16 out.  2-phase:
// 128x128 tile, BK=64, dbuf LDS (As 2x16K bf16 + Bs 2x16K = 64KB, 2 blk/CU).
// Iter t: stage B(t+1)->Bs[nxt] (gload_lds) + issue A(t+1)->regs, THEN
// ds_read+MFMA on [cur], THEN cvt+ds_write A(t+1)->As[nxt], barrier.
// All loads get >=1 compute phase of latency cover before the barrier drain.
// ---------------------------------------------------------------------------
__global__ __launch_bounds__(256) void gemm2ph_f32a(
    const float* __restrict__ A, const unsigned short* __restrict__ BT,
    const float* __restrict__ bias0, unsigned short* __restrict__ out0,
    int Ntiles, int ldc) {
  __shared__ __align__(16) unsigned short As[2][128 * 64];
  __shared__ __align__(16) unsigned short Bs[2][128 * 64];
  const int t = threadIdx.x;
  const int w = t >> 6, l = t & 63, li = l & 15, lg = l >> 4;
  const int wm = w >> 1, wn = w & 1;
  const int K = 512;
  const int q8 = gridDim.x >> 3;
  const int wg = (blockIdx.x & 7) * q8 + (blockIdx.x >> 3);
  const int m0 = (wg / Ntiles) * 128, n0 = (wg % Ntiles) * 128;

  f32x4 acc[4][4] = {};
  const int arow = t >> 4, ac = t & 15;   // A: 16 rows/grp x 16 float4-cols
  const int brow = t >> 3, bslot = t & 7; // B: 32 rows/grp x 8 16B-slots
  float4 areg[8];

#define ISSUE_A(kt)                                                            \
  {                                                                            \
    _Pragma("unroll") for (int i = 0; i < 8; i++)                              \
        areg[i] = *reinterpret_cast<const float4*>(                            \
            &A[(size_t)(m0 + i * 16 + arow) * K + (kt) + ac * 4]);             \
  }
#define STAGE_B(kt, buf)                                                       \
  {                                                                            \
    _Pragma("unroll") for (int i = 0; i < 4; i++) {                            \
      const int row = i * 32 + brow;                                           \
      const int gs = (bslot ^ (row & 7)) * 8;                                  \
      gload16(&BT[(size_t)(n0 + row) * K + (kt) + gs], &Bs[buf][(i * 256 + t) * 8]); \
    }                                                                          \
  }
#define WRITE_A(buf)                                                           \
  {                                                                            \
    _Pragma("unroll") for (int i = 0; i < 8; i++) {                            \
      const int row = i * 16 + arow;                                           \
      u16x4 o;                                                                 \
      o[0] = f2bf_bits(areg[i].x); o[1] = f2bf_bits(areg[i].y);                \
      o[2] = f2bf_bits(areg[i].z); o[3] = f2bf_bits(areg[i].w);                \
      *reinterpret_cast<u16x4*>(                                               \
          &As[buf][row * 64 + (((ac >> 1) ^ (row & 7)) * 8) + (ac & 1) * 4]) = o; \
    }                                                                          \
  }

  // ---- prologue: tile 0 ----
  ISSUE_A(0);
  STAGE_B(0, 0);
  WRITE_A(0);        // compiler waits on areg deps only
  __syncthreads();   // Bs[0] DMA drained, As[0] visible

#pragma unroll 2
  for (int tt = 0; tt < 8; tt++) {
    const int cur = tt & 1, nxt = cur ^ 1;
    const int ktn = (tt + 1) * 64;
    if (tt < 7) {
      STAGE_B(ktn, nxt);   // covered by this whole iter
      ISSUE_A(ktn);        // covered by ds_read+MFMA below
    }
    // ---- compute tile tt ----
#pragma unroll
    for (int kk = 0; kk < 2; kk++) {
      bf16x8 a[4], b[4];
#pragma unroll
      for (int mf = 0; mf < 4; mf++) {
        const int r = wm * 64 + mf * 16 + li;
        a[mf] = *reinterpret_cast<const bf16x8*>(
            &As[cur][r * 64 + (((kk * 4 + lg) ^ (r & 7)) * 8)]);
      }
#pragma unroll
      for (int nf = 0; nf < 4; nf++) {
        const int r = wn * 64 + nf * 16 + li;
        b[nf] = *reinterpret_cast<const bf16x8*>(
            &Bs[cur][r * 64 + (((kk * 4 + lg) ^ (r & 7)) * 8)]);
      }
#pragma unroll
      for (int mf = 0; mf < 4; mf++)
#pragma unroll
        for (int nf = 0; nf < 4; nf++)
          acc[mf][nf] = MFMA16(a[mf], b[nf], acc[mf][nf]);
    }
    if (tt < 7) WRITE_A(nxt);  // As[nxt] free since last barrier
    __syncthreads();
  }
#undef ISSUE_A
#undef STAGE_B
#undef WRITE_A

  const int lg4 = lg * 4;
#pragma unroll
  for (int nf = 0; nf < 4; nf++) {
    const int col = n0 + wn * 64 + nf * 16 + li;
    const float bv = bias0[col];
#pragma unroll
    for (int mf = 0; mf < 4; mf++) {
      const int row = m0 + wm * 64 + mf * 16 + lg4;
#pragma unroll
      for (int r = 0; r < 4; r++)
        out0[(size_t)(row + r) * ldc + col] = f2bf_bits(acc[mf][nf][r] + bv);
    }
  }
}

// ---------------------------------------------------------------------------
// gemm2ph_bf16f: bf16 A & B, both gload_lds dbuf, 2-phase, fp32 out + bias.
// ---------------------------------------------------------------------------
__global__ __launch_bounds__(256) void gemm2ph_bf16f(
    const unsigned short* __restrict__ A, const unsigned short* __restrict__ BT,
    const float* __restrict__ bias0, float* __restrict__ out0,
    int Ntiles, int ldc) {
  __shared__ __align__(16) unsigned short As[2][128 * 64];
  __shared__ __align__(16) unsigned short Bs[2][128 * 64];
  const int t = threadIdx.x;
  const int w = t >> 6, l = t & 63, li = l & 15, lg = l >> 4;
  const int wm = w >> 1, wn = w & 1;
  const int K = 512;
  const int q8 = gridDim.x >> 3;
  const int wg = (blockIdx.x & 7) * q8 + (blockIdx.x >> 3);
  const int m0 = (wg / Ntiles) * 128, n0 = (wg % Ntiles) * 128;

  f32x4 acc[4][4] = {};
  const int sr = t >> 3, sslot = t & 7;

#define STAGE_AB(kt, buf)                                                      \
  {                                                                            \
    _Pragma("unroll") for (int i = 0; i < 4; i++) {                            \
      const int row = i * 32 + sr;                                             \
      const int gs = (sslot ^ (row & 7)) * 8;                                  \
      gload16(&A[(size_t)(m0 + row) * K + (kt) + gs], &As[buf][(i * 256 + t) * 8]); \
      gload16(&BT[(size_t)(n0 + row) * K + (kt) + gs], &Bs[buf][(i * 256 + t) * 8]); \
    }                                                                          \
  }

  STAGE_AB(0, 0);
  __syncthreads();

#pragma unroll 2
  for (int tt = 0; tt < 8; tt++) {
    const int cur = tt & 1, nxt = cur ^ 1;
    if (tt < 7) STAGE_AB((tt + 1) * 64, nxt);
#pragma unroll
    for (int kk = 0; kk < 2; kk++) {
      bf16x8 a[4], b[4];
#pragma unroll
      for (int mf = 0; mf < 4; mf++) {
        const int r = wm * 64 + mf * 16 + li;
        a[mf] = *reinterpret_cast<const bf16x8*>(
            &As[cur][r * 64 + (((kk * 4 + lg) ^ (r & 7)) * 8)]);
      }
#pragma unroll
      for (int nf = 0; nf < 4; nf++) {
        const int r = wn * 64 + nf * 16 + li;
        b[nf] = *reinterpret_cast<const bf16x8*>(
            &Bs[cur][r * 64 + (((kk * 4 + lg) ^ (r & 7)) * 8)]);
      }
#pragma unroll
      for (int mf = 0; mf < 4; mf++)
#pragma unroll
        for (int nf = 0; nf < 4; nf++)
          acc[mf][nf] = MFMA16(a[mf], b[nf], acc[mf][nf]);
    }
    __syncthreads();
  }
#undef STAGE_AB

  const int lg4 = lg * 4;
#pragma unroll
  for (int nf = 0; nf < 4; nf++) {
    const int col = n0 + wn * 64 + nf * 16 + li;
    const float bv = bias0[col];
#pragma unroll
    for (int mf = 0; mf < 4; mf++) {
      const int row = m0 + wm * 64 + mf * 16 + lg4;
#pragma unroll
      for (int r = 0; r < 4; r++)
        out0[(size_t)(row + r) * ldc + col] = acc[mf][nf][r] + bv;
    }
  }
}

// ---------------------------------------------------------------------------
// 128x128 bf16 GEMM (1-phase) for the small kv/pc GEMM, N=1536 split output.
// ---------------------------------------------------------------------------
__global__ __launch_bounds__(256) void gemm_kvpc(
    const unsigned short* __restrict__ A, const unsigned short* __restrict__ BT,
    const float* __restrict__ bias0, const float* __restrict__ bias1,
    const float* __restrict__ bias2, unsigned short* out0, unsigned short* out1,
    float* out2, int Ntiles) {
  __shared__ __align__(16) unsigned short As[128 * 64];
  __shared__ __align__(16) unsigned short Bs[128 * 64];
  const int t = threadIdx.x;
  const int w = t >> 6, l = t & 63, li = l & 15, lg = l >> 4;
  const int wm = w >> 1, wn = w & 1;
  const int K = 512;
  const int m0 = (blockIdx.x / Ntiles) * 128, n0 = (blockIdx.x % Ntiles) * 128;

  f32x4 acc[4][4] = {};
  const int sr = t >> 3, sslot = t & 7;

  for (int kt = 0; kt < K; kt += 64) {
#pragma unroll
    for (int i = 0; i < 4; i++) {
      const int row = i * 32 + sr;
      const int gs = (sslot ^ (row & 7)) * 8;
      gload16(&A[(size_t)(m0 + row) * K + kt + gs], &As[(i * 256 + t) * 8]);
      gload16(&BT[(size_t)(n0 + row) * K + kt + gs], &Bs[(i * 256 + t) * 8]);
    }
    __syncthreads();
#pragma unroll
    for (int kk = 0; kk < 2; kk++) {
      bf16x8 a[4], b[4];
#pragma unroll
      for (int mf = 0; mf < 4; mf++) {
        const int r = wm * 64 + mf * 16 + li;
        a[mf] = *reinterpret_cast<const bf16x8*>(&As[r * 64 + (((kk * 4 + lg) ^ (r & 7)) * 8)]);
      }
#pragma unroll
      for (int nf = 0; nf < 4; nf++) {
        const int r = wn * 64 + nf * 16 + li;
        b[nf] = *reinterpret_cast<const bf16x8*>(&Bs[r * 64 + (((kk * 4 + lg) ^ (r & 7)) * 8)]);
      }
#pragma unroll
      for (int mf = 0; mf < 4; mf++)
#pragma unroll
        for (int nf = 0; nf < 4; nf++)
          acc[mf][nf] = MFMA16(a[mf], b[nf], acc[mf][nf]);
    }
    __syncthreads();
  }

  const int lg4 = lg * 4;
#pragma unroll
  for (int nf = 0; nf < 4; nf++) {
    const int col = n0 + wn * 64 + nf * 16 + li;
    if (col < 512) {
      const float bv = bias0[col];
#pragma unroll
      for (int mf = 0; mf < 4; mf++) {
        const int row = m0 + wm * 64 + mf * 16 + lg4;
#pragma unroll
        for (int r = 0; r < 4; r++)
          out0[(size_t)(row + r) * 512 + col] = f2bf_bits(acc[mf][nf][r] + bv);
      }
    } else if (col < 1024) {
      const float bv = bias1[col - 512];
#pragma unroll
      for (int mf = 0; mf < 4; mf++) {
        const int row = m0 + wm * 64 + mf * 16 + lg4;
#pragma unroll
        for (int r = 0; r < 4; r++)
          out1[(size_t)(row + r) * 512 + col - 512] = f2bf_bits(acc[mf][nf][r] + bv);
      }
    } else {
      const float bv = bias2[col - 1024];
#pragma unroll
      for (int mf = 0; mf < 4; mf++) {
        const int row = m0 + wm * 64 + mf * 16 + lg4;
#pragma unroll
        for (int r = 0; r < 4; r++)
          out2[(size_t)(row + r) * 512 + col - 1024] = acc[mf][nf][r] + bv;
      }
    }
  }
}

// ---------------------------------------------------------------------------
// fp32-A 128x128 GEMM (register-staged convert) — tiny pq projection only.
// ---------------------------------------------------------------------------
__global__ __launch_bounds__(256) void gemm_f32a(
    const float* __restrict__ A, const unsigned short* __restrict__ BT,
    const float* __restrict__ bias0, unsigned short* __restrict__ out,
    int K, int ldc) {
  __shared__ __align__(16) unsigned short As[128 * 72];
  __shared__ __align__(16) unsigned short Bs[128 * 72];
  const int t = threadIdx.x;
  const int w = t >> 6, l = t & 63, li = l & 15, lg = l >> 4;
  const int wm = w >> 1, wn = w & 1;
  const int m0 = blockIdx.x * 128, n0 = blockIdx.y * 128;

  f32x4 acc[4][4] = {};

  for (int kt = 0; kt < K; kt += 64) {
#pragma unroll
    for (int i = 0; i < 8; i++) {
      const int row = i * 16 + (t >> 4), k = (t & 15) * 4;
      const float4 v = *reinterpret_cast<const float4*>(&A[(size_t)(m0 + row) * K + kt + k]);
      u16x4 o;
      o[0] = f2bf_bits(v.x); o[1] = f2bf_bits(v.y);
      o[2] = f2bf_bits(v.z); o[3] = f2bf_bits(v.w);
      *reinterpret_cast<u16x4*>(&As[row * 72 + k]) = o;
    }
#pragma unroll
    for (int i = 0; i < 4; i++) {
      const int row = i * 32 + (t >> 3), k = (t & 7) * 8;
      const u16x8 v = *reinterpret_cast<const u16x8*>(&BT[(size_t)(n0 + row) * K + kt + k]);
      *reinterpret_cast<u16x8*>(&Bs[row * 72 + k]) = v;
    }
    __syncthreads();
#pragma unroll
    for (int kk = 0; kk < 2; kk++) {
      bf16x8 a[4], b[4];
#pragma unroll
      for (int mf = 0; mf < 4; mf++)
        a[mf] = *reinterpret_cast<const bf16x8*>(&As[(wm * 64 + mf * 16 + li) * 72 + kk * 32 + lg * 8]);
#pragma unroll
      for (int nf = 0; nf < 4; nf++)
        b[nf] = *reinterpret_cast<const bf16x8*>(&Bs[(wn * 64 + nf * 16 + li) * 72 + kk * 32 + lg * 8]);
#pragma unroll
      for (int mf = 0; mf < 4; mf++)
#pragma unroll
        for (int nf = 0; nf < 4; nf++)
          acc[mf][nf] = MFMA16(a[mf], b[nf], acc[mf][nf]);
    }
    __syncthreads();
  }
  const int lg4 = lg * 4;
#pragma unroll
  for (int nf = 0; nf < 4; nf++) {
    const int col = n0 + wn * 64 + nf * 16 + li;
    const float bv = bias0[col];
#pragma unroll
    for (int mf = 0; mf < 4; mf++) {
      const int row = m0 + wm * 64 + mf * 16 + lg4;
#pragma unroll
      for (int r = 0; r < 4; r++)
        out[(size_t)(row + r) * ldc + col] = f2bf_bits(acc[mf][nf][r] + bv);
    }
  }
}

// ---------------------------------------------------------------------------
// Pack attention, split over S. grid (128 bh, 8 chunks), block 256 (4 waves).
// ---------------------------------------------------------------------------
__global__ __launch_bounds__(256) void pack_attn(
    const unsigned short* __restrict__ pq_buf,
    const unsigned short* __restrict__ pkv_buf, float* __restrict__ partial) {
  __shared__ __align__(16) unsigned short pkL[64 * 72];
  __shared__ __align__(16) unsigned short pvT[64 * 72];
  __shared__ __align__(16) unsigned short prL[4 * 16 * 72];
  const int t = threadIdx.x, w = t >> 6, l = t & 63, li = l & 15, lg = l >> 4;
  const int bh = blockIdx.x, b = bh >> 3, h = bh & 7;
  const int sb = blockIdx.y * 512;

  bf16x8 aq[2];
  {
    const size_t base = ((size_t)(b * 64 + w * 16 + li)) * 512 + h * 64;
    aq[0] = *reinterpret_cast<const bf16x8*>(&pq_buf[base + lg * 8]);
    aq[1] = *reinterpret_cast<const bf16x8*>(&pq_buf[base + 32 + lg * 8]);
  }

  f32x4 acc[4] = {};
  float lsum[4] = {};

  for (int st = 0; st < 8; st++) {
    const int s0 = sb + st * 64;
#pragma unroll
    for (int i = 0; i < 2; i++) {
      const int row = i * 32 + (t >> 3), c = (t & 7) * 8;
      const u16x8 v = *reinterpret_cast<const u16x8*>(
          &pkv_buf[((size_t)(b * 4096 + s0 + row)) * 1024 + h * 64 + c]);
      *reinterpret_cast<u16x8*>(&pkL[row * 72 + c]) = v;
    }
    {
      const int rp = t >> 3, c = (t & 7) * 8;
      const size_t base = ((size_t)(b * 4096 + s0 + 2 * rp)) * 1024 + 512 + h * 64 + c;
      const u16x8 u0 = *reinterpret_cast<const u16x8*>(&pkv_buf[base]);
      const u16x8 u1 = *reinterpret_cast<const u16x8*>(&pkv_buf[base + 1024]);
#pragma unroll
      for (int j = 0; j < 8; j++) {
        const int val = ((int)u0[j] & 0xffff) | ((int)u1[j] << 16);
        *reinterpret_cast<int*>(&pvT[(c + j) * 72 + 2 * rp]) = val;
      }
    }
    __syncthreads();
    f32x4 sc[4] = {};
#pragma unroll
    for (int nf = 0; nf < 4; nf++) {
#pragma unroll
      for (int kk = 0; kk < 2; kk++) {
        const bf16x8 bk = *reinterpret_cast<const bf16x8*>(
            &pkL[(nf * 16 + li) * 72 + kk * 32 + lg * 8]);
        sc[nf] = MFMA16(aq[kk], bk, sc[nf]);
      }
    }
#pragma unroll
    for (int nf = 0; nf < 4; nf++) {
#pragma unroll
      for (int r = 0; r < 4; r++) {
        const float e = __expf(sc[nf][r]);
        lsum[r] += e;
        prL[(w * 16 + lg * 4 + r) * 72 + nf * 16 + li] = f2bf_bits(e);
      }
    }
#pragma unroll
    for (int kk = 0; kk < 2; kk++) {
      const bf16x8 ap = *reinterpret_cast<const bf16x8*>(
          &prL[(w * 16 + li) * 72 + kk * 32 + lg * 8]);
#pragma unroll
      for (int nf = 0; nf < 4; nf++) {
        const bf16x8 bv = *reinterpret_cast<const bf16x8*>(
            &pvT[(nf * 16 + li) * 72 + kk * 32 + lg * 8]);
        acc[nf] = MFMA16(ap, bv, acc[nf]);
      }
    }
    __syncthreads();
  }

#pragma unroll
  for (int m = 1; m < 16; m <<= 1)
#pragma unroll
    for (int r = 0; r < 4; r++) lsum[r] += __shfl_xor(lsum[r], m);

  const size_t pbase = ((size_t)(bh * 8 + blockIdx.y)) * 4160;
#pragma unroll
  for (int nf = 0; nf < 4; nf++)
#pragma unroll
    for (int r = 0; r < 4; r++)
      partial[pbase + (size_t)(w * 16 + lg * 4 + r) * 64 + nf * 16 + li] = acc[nf][r];
  if (li == 0)
#pragma unroll
    for (int r = 0; r < 4; r++) partial[pbase + 4096 + w * 16 + lg * 4 + r] = lsum[r];
}

__global__ __launch_bounds__(256) void pack_combine(const float* __restrict__ partial,
                                                    unsigned short* __restrict__ pc_buf) {
  const int bh = blockIdx.x, b = bh >> 3, h = bh & 7;
  const int t = threadIdx.x;
#pragma unroll
  for (int e = 0; e < 16; e++) {
    const int idx = e * 256 + t;
    const int p = idx >> 6, d = idx & 63;
    float s = 0.f, den = 0.f;
#pragma unroll
    for (int c = 0; c < 8; c++) {
      const float* pb = &partial[((size_t)(bh * 8 + c)) * 4160];
      s += pb[idx];
      den += pb[4096 + p];
    }
    pc_buf[((size_t)(b * 64 + p)) * 512 + h * 64 + d] = f2bf_bits(s / den);
  }
}

// ---------------------------------------------------------------------------
// Unpack attention. grid (16 s-tiles, 128 bh), block 256 (4 waves x 64 s-rows).
// ---------------------------------------------------------------------------
__global__ __launch_bounds__(256) void unpack_attn(
    const unsigned short* q_in, const unsigned short* __restrict__ k_buf,
    const unsigned short* __restrict__ v_buf, float* __restrict__ aw_out,
    unsigned short* attnh_out) {
  __shared__ __align__(16) unsigned short kL[64 * 72];
  __shared__ __align__(16) unsigned short vT[64 * 72];
  __shared__ __align__(16) unsigned short prL[4 * 64 * 72];
  const int t = threadIdx.x, w = t >> 6, l = t & 63, li = l & 15, lg = l >> 4;
  const int bh = blockIdx.y, b = bh >> 3, h = bh & 7;
  const int sbase = blockIdx.x * 256 + w * 64;

#pragma unroll
  for (int i = 0; i < 2; i++) {
    const int p = i * 32 + (t >> 3), c = (t & 7) * 8;
    const u16x8 v = *reinterpret_cast<const u16x8*>(
        &k_buf[((size_t)(b * 64 + p)) * 512 + h * 64 + c]);
    *reinterpret_cast<u16x8*>(&kL[p * 72 + c]) = v;
  }
  {
    const int rp = t >> 3, c = (t & 7) * 8;
    const size_t base = ((size_t)(b * 64 + 2 * rp)) * 512 + h * 64 + c;
    const u16x8 u0 = *reinterpret_cast<const u16x8*>(&v_buf[base]);
    const u16x8 u1 = *reinterpret_cast<const u16x8*>(&v_buf[base + 512]);
#pragma unroll
    for (int j = 0; j < 8; j++) {
      const int val = ((int)u0[j] & 0xffff) | ((int)u1[j] << 16);
      *reinterpret_cast<int*>(&vT[(c + j) * 72 + 2 * rp]) = val;
    }
  }
  bf16x8 aq[4][2];
#pragma unroll
  for (int mf = 0; mf < 4; mf++) {
    const size_t base = ((size_t)(b * 4096 + sbase + mf * 16 + li)) * 512 + h * 64;
    aq[mf][0] = *reinterpret_cast<const bf16x8*>(&q_in[base + lg * 8]);
    aq[mf][1] = *reinterpret_cast<const bf16x8*>(&q_in[base + 32 + lg * 8]);
  }
  __syncthreads();

  f32x4 sc[4][4] = {};
#pragma unroll
  for (int kk = 0; kk < 2; kk++)
#pragma unroll
    for (int nf = 0; nf < 4; nf++) {
      const bf16x8 bk = *reinterpret_cast<const bf16x8*>(
          &kL[(nf * 16 + li) * 72 + kk * 32 + lg * 8]);
#pragma unroll
      for (int mf = 0; mf < 4; mf++) sc[mf][nf] = MFMA16(aq[mf][kk], bk, sc[mf][nf]);
    }

#pragma unroll
  for (int mf = 0; mf < 4; mf++) {
#pragma unroll
    for (int r = 0; r < 4; r++) {
      float e[4];
      float rs = 0.f;
#pragma unroll
      for (int nf = 0; nf < 4; nf++) {
        e[nf] = __expf(sc[mf][nf][r]);
        rs += e[nf];
      }
#pragma unroll
      for (int m = 1; m < 16; m <<= 1) rs += __shfl_xor(rs, m);
      const float inv = 1.0f / rs;
      const int srow = sbase + mf * 16 + lg * 4 + r;
#pragma unroll
      for (int nf = 0; nf < 4; nf++) {
        const float pr = e[nf] * inv;
        aw_out[(size_t)srow * 8192 + bh * 64 + nf * 16 + li] = pr;
        prL[(w * 64 + mf * 16 + lg * 4 + r) * 72 + nf * 16 + li] = f2bf_bits(pr);
      }
    }
  }

  f32x4 acc[4][4] = {};
#pragma unroll
  for (int kk = 0; kk < 2; kk++)
#pragma unroll
    for (int mf = 0; mf < 4; mf++) {
      const bf16x8 ap = *reinterpret_cast<const bf16x8*>(
          &prL[(w * 64 + mf * 16 + li) * 72 + kk * 32 + lg * 8]);
#pragma unroll
      for (int nf = 0; nf < 4; nf++) {
        const bf16x8 bv = *reinterpret_cast<const bf16x8*>(
            &vT[(nf * 16 + li) * 72 + kk * 32 + lg * 8]);
        acc[mf][nf] = MFMA16(ap, bv, acc[mf][nf]);
      }
    }
#pragma unroll
  for (int mf = 0; mf < 4; mf++)
#pragma unroll
    for (int nf = 0; nf < 4; nf++)
#pragma unroll
      for (int r = 0; r < 4; r++)
        attnh_out[((size_t)(b * 4096 + sbase + mf * 16 + lg * 4 + r)) * 512 + h * 64 +
                  nf * 16 + li] = f2bf_bits(acc[mf][nf][r]);
}

// ---------------------------------------------------------------------------
extern "C" void kernel_launch(void* const* d_in, const int* in_sizes, int n_in,
                              void* d_out, int out_size, void* d_ws, size_t ws_size,
                              hipStream_t stream) {
  (void)in_sizes; (void)n_in; (void)out_size; (void)ws_size;

  const float* query   = (const float*)d_in[0];
  const float* pquery  = (const float*)d_in[1];
  const float* context = (const float*)d_in[2];
  const float* Wi  = (const float*)d_in[3];  const float* bi  = (const float*)d_in[4];
  const float* Wip = (const float*)d_in[5];  const float* bip = (const float*)d_in[6];
  const float* Wic = (const float*)d_in[7];  const float* bic = (const float*)d_in[8];
  const float* Wq  = (const float*)d_in[9];  const float* bq  = (const float*)d_in[10];
  const float* Wpq = (const float*)d_in[11]; const float* bpq = (const float*)d_in[12];
  const float* Wk  = (const float*)d_in[13]; const float* bk  = (const float*)d_in[14];
  const float* Wpk = (const float*)d_in[15]; const float* bpk = (const float*)d_in[16];
  const float* Wv  = (const float*)d_in[17]; const float* bv  = (const float*)d_in[18];
  const float* Wpv = (const float*)d_in[19]; const float* bpv = (const float*)d_in[20];
  const float* Wo  = (const float*)d_in[21]; const float* bo  = (const float*)d_in[22];
  const float* Wop = (const float*)d_in[23]; const float* bop = (const float*)d_in[24];

  // ---- workspace layout ----
  char* ws = (char*)d_ws;
  unsigned short* WT     = (unsigned short*)(ws);                 // 8 x 512x512 bf16
  unsigned short* WqeT   = (unsigned short*)(ws + 4u * 1024 * 1024);
  unsigned short* WpqeT  = WqeT + 512 * 512;
  unsigned short* WpkveT = WpqeT + 512 * 512;                     // 1024 x 512
  float* bqe   = (float*)(WpkveT + (size_t)1024 * 512);
  float* bpqe  = bqe + 512;
  float* bpkve = bpqe + 512;
  unsigned short* q_buf   = (unsigned short*)(ws + 8u * 1024 * 1024);  // 65536x512 (later attn_h)
  unsigned short* pkv_buf = q_buf + (size_t)65536 * 512;               // 65536x1024
  unsigned short* pq_buf  = pkv_buf + (size_t)65536 * 1024;
  unsigned short* pc_buf  = pq_buf + (size_t)1024 * 512;
  unsigned short* k_buf   = pc_buf + (size_t)1024 * 512;
  unsigned short* v_buf   = k_buf + (size_t)1024 * 512;
  float* partial = (float*)(v_buf + (size_t)1024 * 512);               // 1024 x 4160 f32

  float* out_attn = (float*)d_out;                       // (B,S,512) fp32
  float* out_pc   = out_attn + (size_t)16 * 4096 * 512;  // (B,P,512)
  float* out_aw   = out_pc + (size_t)16 * 64 * 512;      // (S,B*H,P)

  const dim3 blk(256);

  // 1) weight prep
  Ptr8 tsrc; tsrc.p[0]=Wq; tsrc.p[1]=Wpq; tsrc.p[2]=Wpk; tsrc.p[3]=Wpv;
  tsrc.p[4]=Wk; tsrc.p[5]=Wv; tsrc.p[6]=Wop; tsrc.p[7]=Wo;
  prep_kernel<<<dim3(16, 16, 9), blk, 0, stream>>>(
      tsrc, WT, bi, bip, bic, Wq, Wpq, Wpk, Wpv, bq, bpq, bpk, bpv, bqe);
  gemm_wcomb<<<dim3(4, 4, 4), blk, 0, stream>>>(Wi, Wip, Wic, WT, WqeT);

  // 2) projections — 2-phase pipelined GEMMs
  gemm2ph_f32a<<<dim3(2048), blk, 0, stream>>>(query, WqeT, bqe, q_buf, 4, 512);
  gemm2ph_f32a<<<dim3(4096), blk, 0, stream>>>(context, WpkveT, bpkve, pkv_buf, 8, 1024);
  gemm_f32a<<<dim3(8, 4), blk, 0, stream>>>(pquery, WpqeT, bpqe, pq_buf, 512, 512);

  // 3) pack attention (8 chunks) + combine -> pc
  pack_attn<<<dim3(128, 8), blk, 0, stream>>>(pq_buf, pkv_buf, partial);
  pack_combine<<<128, blk, 0, stream>>>(partial, pc_buf);

  // 4) k, v, pc_out (fused N=1536)
  gemm_kvpc<<<dim3(96), blk, 0, stream>>>(
      pc_buf, WT + (size_t)4 * 262144, bk, bv, bop, k_buf, v_buf, out_pc, 12);

  // 5) unpack attention: aw_t out + attn_h in-place over q_buf
  unpack_attn<<<dim3(16, 128), blk, 0, stream>>>(q_buf, k_buf, v_buf, out_aw, q_buf);

  // 6) final projection: attn = attn_h @ Wo + bo (2-phase)
  gemm2ph_bf16f<<<dim3(2048), blk, 0, stream>>>(
      q_buf, WT + (size_t)7 * 262144, bo, out_attn, 4, 512);
}

// Round 6
// 504.791 us; speedup vs baseline: 1.0715x; 1.0715x over previous
//
#include <hip/hip_runtime.h>

// ---------------------------------------------------------------------------
// LUNA fused pipeline for MI355X / gfx950.  B=16, S=4096, P=64, QKV=512, H=8.
// R6: BK=32 2-phase GEMM, 36KB LDS -> 4 blocks/CU (16 waves), launch_bounds
//     (256,4) to pin VGPR<=128.  A fp32 reg-staged->bf16 ds_write (pad-40
//     rows, 2-way banks); B gload_lds w/ slot^((row>>1)&3) source swizzle.
//     q+pkv+pq merged into ONE launch (grid 6176).  8 launches total.
// ---------------------------------------------------------------------------

typedef __bf16 bf16x8 __attribute__((ext_vector_type(8)));
typedef float f32x4 __attribute__((ext_vector_type(4)));
typedef unsigned short u16x8 __attribute__((ext_vector_type(8)));
typedef unsigned short u16x4 __attribute__((ext_vector_type(4)));

#define MFMA16(a, b, c) __builtin_amdgcn_mfma_f32_16x16x32_bf16((a), (b), (c), 0, 0, 0)

__device__ __forceinline__ unsigned short f2bf_bits(float f) {
  unsigned int u = __float_as_uint(f);
  u += 0x7fffu + ((u >> 16) & 1u);  // RTNE (finite inputs)
  return (unsigned short)(u >> 16);
}

__device__ __forceinline__ void gload16(const void* g, void* l) {
  __builtin_amdgcn_global_load_lds(
      (const __attribute__((address_space(1))) void*)g,
      (__attribute__((address_space(3))) void*)l, 16, 0, 0);
}

// ---------------------------------------------------------------------------
// prep: z 0..7 -> transpose+convert W_z into bf16 W^T; z==8 -> combined biases.
// ---------------------------------------------------------------------------
struct Ptr8 { const float* p[8]; };

__global__ __launch_bounds__(256) void prep_kernel(
    Ptr8 srcs, unsigned short* __restrict__ WT,
    const float* bi, const float* bip, const float* bic,
    const float* Wq, const float* Wpq, const float* Wpk, const float* Wpv,
    const float* bq, const float* bpq, const float* bpk, const float* bpv,
    float* __restrict__ bias_out) {
  const int t = threadIdx.x;
  if (blockIdx.z < 8) {
    const float* __restrict__ W = srcs.p[blockIdx.z];
    unsigned short* __restrict__ O = WT + (size_t)blockIdx.z * 262144;
    __shared__ float tile[32][33];
    const int tr = blockIdx.x * 32, tc = blockIdx.y * 32;
    {
      const int r = t >> 3, c4 = (t & 7) * 4;
      const float4 v = *reinterpret_cast<const float4*>(&W[(size_t)(tr + r) * 512 + tc + c4]);
      tile[r][c4 + 0] = v.x; tile[r][c4 + 1] = v.y; tile[r][c4 + 2] = v.z; tile[r][c4 + 3] = v.w;
    }
    __syncthreads();
    {
      const int n = t >> 3, k4 = (t & 7) * 4;
      u16x4 o;
#pragma unroll
      for (int j = 0; j < 4; j++) o[j] = f2bf_bits(tile[k4 + j][n]);
      *reinterpret_cast<u16x4*>(&O[(size_t)(tc + n) * 512 + tr + k4]) = o;
    }
  } else {
    const int idx = blockIdx.y * 16 + blockIdx.x;
    if (idx >= 8) return;
    const int y = idx >> 1;
    const float* bin  = (y == 0) ? bi : (y == 1) ? bip : bic;
    const float* W    = (y == 0) ? Wq : (y == 1) ? Wpq : (y == 2) ? Wpk : Wpv;
    const float* bout = (y == 0) ? bq : (y == 1) ? bpq : (y == 2) ? bpk : bpv;
    const float scale = (y < 2) ? 0.125f : 1.0f;
    const int n = (idx & 1) * 256 + t;
    float s = 0.f;
    for (int k = 0; k < 512; k++) s += bin[k] * W[(size_t)k * 512 + n];
    bias_out[y * 512 + n] = (s + bout[n]) * scale;
  }
}

// ---------------------------------------------------------------------------
// Batched weight-combine: out_z^T = scale_z * (A_z @ WT_z^T), z in 0..3.
// ---------------------------------------------------------------------------
__global__ __launch_bounds__(256) void gemm_wcomb(
    const float* __restrict__ Wi, const float* __restrict__ Wip,
    const float* __restrict__ Wic, const unsigned short* __restrict__ WTbase,
    unsigned short* __restrict__ outbase) {
  const int z = blockIdx.z;
  const float* __restrict__ A = (z == 0) ? Wi : (z == 1) ? Wip : Wic;
  const unsigned short* __restrict__ BT = WTbase + (size_t)z * 262144;
  unsigned short* __restrict__ out = outbase + (size_t)z * 262144;
  const float scale = (z < 2) ? 0.125f : 1.0f;

  __shared__ __align__(16) unsigned short As[128 * 72];
  __shared__ __align__(16) unsigned short Bs[128 * 72];
  const int t = threadIdx.x;
  const int w = t >> 6, l = t & 63, li = l & 15, lg = l >> 4;
  const int wm = w >> 1, wn = w & 1;
  const int m0 = blockIdx.x * 128, n0 = blockIdx.y * 128;

  f32x4 acc[4][4] = {};

  for (int kt = 0; kt < 512; kt += 64) {
#pragma unroll
    for (int i = 0; i < 8; i++) {
      const int row = i * 16 + (t >> 4), k = (t & 15) * 4;
      const float4 v = *reinterpret_cast<const float4*>(&A[(size_t)(m0 + row) * 512 + kt + k]);
      u16x4 o;
      o[0] = f2bf_bits(v.x); o[1] = f2bf_bits(v.y);
      o[2] = f2bf_bits(v.z); o[3] = f2bf_bits(v.w);
      *reinterpret_cast<u16x4*>(&As[row * 72 + k]) = o;
    }
#pragma unroll
    for (int i = 0; i < 4; i++) {
      const int row = i * 32 + (t >> 3), k = (t & 7) * 8;
      const u16x8 v = *reinterpret_cast<const u16x8*>(&BT[(size_t)(n0 + row) * 512 + kt + k]);
      *reinterpret_cast<u16x8*>(&Bs[row * 72 + k]) = v;
    }
    __syncthreads();
#pragma unroll
    for (int kk = 0; kk < 2; kk++) {
      bf16x8 a[4], b[4];
#pragma unroll
      for (int mf = 0; mf < 4; mf++)
        a[mf] = *reinterpret_cast<const bf16x8*>(&As[(wm * 64 + mf * 16 + li) * 72 + kk * 32 + lg * 8]);
#pragma unroll
      for (int nf = 0; nf < 4; nf++)
        b[nf] = *reinterpret_cast<const bf16x8*>(&Bs[(wn * 64 + nf * 16 + li) * 72 + kk * 32 + lg * 8]);
#pragma unroll
      for (int mf = 0; mf < 4; mf++)
#pragma unroll
        for (int nf = 0; nf < 4; nf++)
          acc[mf][nf] = MFMA16(a[mf], b[nf], acc[mf][nf]);
    }
    __syncthreads();
  }
  const int lg4 = lg * 4;
#pragma unroll
  for (int nf = 0; nf < 4; nf++) {
    const int col = n0 + wn * 64 + nf * 16 + li;
#pragma unroll
    for (int mf = 0; mf < 4; mf++) {
      const int row = m0 + wm * 64 + mf * 16 + lg4;
#pragma unroll
      for (int r = 0; r < 4; r++)
        out[(size_t)col * 512 + row + r] = f2bf_bits(acc[mf][nf][r] * scale);
    }
  }
}

// ---------------------------------------------------------------------------
// gemm2ph_body: C[128 x 128-tile] = bf16(A) @ BT^T + bias.  BK=32, 2-phase
// dbuf, 36KB LDS (4 blocks/CU).  A: global->reg->cvt->ds_write into pad-40
// rows (bank groups (row*5+lg)%8 -> all 8, 2-way free).  B: gload_lds linear
// dest, source slot pre-swizzled slot^((row>>1)&3) (all 8 groups, 2-way).
// Loads for tile t+1 issued before MFMA of tile t (full compute-phase cover).
// ---------------------------------------------------------------------------
template <typename AT, int OUTF32>
__device__ __forceinline__ void gemm2ph_body(
    const AT* __restrict__ A, const unsigned short* __restrict__ BT,
    const float* __restrict__ bias, void* out, int Ntiles, int ldc, int wg) {
  __shared__ __align__(16) unsigned short As[2][128 * 40];  // 2 x 10 KB
  __shared__ __align__(16) unsigned short Bs[2][128 * 32];  // 2 x  8 KB
  const int t = threadIdx.x;
  const int w = t >> 6, l = t & 63, li = l & 15, lg = l >> 4;
  const int wm = w >> 1, wn = w & 1;
  const int K = 512;
  const int m0 = (wg / Ntiles) * 128, n0 = (wg % Ntiles) * 128;

  f32x4 acc[4][4] = {};
  float4 aregf[4];
  u16x8 aregh[2];
  const int brow_ = t >> 2, bslot_ = t & 3;

#define ISSUE_A(kt)                                                            \
  if constexpr (sizeof(AT) == 4) {                                             \
    _Pragma("unroll") for (int i = 0; i < 4; i++)                              \
        aregf[i] = *reinterpret_cast<const float4*>(                           \
            &A[(size_t)(m0 + i * 32 + (t >> 3)) * K + (kt) + (t & 7) * 4]);    \
  } else {                                                                     \
    _Pragma("unroll") for (int i = 0; i < 2; i++)                              \
        aregh[i] = *reinterpret_cast<const u16x8*>(                            \
            &A[(size_t)(m0 + i * 64 + (t >> 2)) * K + (kt) + (t & 3) * 8]);    \
  }

#define WRITE_A(buf)                                                           \
  if constexpr (sizeof(AT) == 4) {                                             \
    _Pragma("unroll") for (int i = 0; i < 4; i++) {                            \
      const int row = i * 32 + (t >> 3);                                       \
      u16x4 o;                                                                 \
      o[0] = f2bf_bits(aregf[i].x); o[1] = f2bf_bits(aregf[i].y);              \
      o[2] = f2bf_bits(aregf[i].z); o[3] = f2bf_bits(aregf[i].w);              \
      *reinterpret_cast<u16x4*>(&As[buf][row * 40 + (t & 7) * 4]) = o;         \
    }                                                                          \
  } else {                                                                     \
    _Pragma("unroll") for (int i = 0; i < 2; i++) {                            \
      const int row = i * 64 + (t >> 2);                                       \
      *reinterpret_cast<u16x8*>(&As[buf][row * 40 + (t & 3) * 8]) = aregh[i];  \
    }                                                                          \
  }

#define STAGE_B(kt, buf)                                                       \
  {                                                                            \
    _Pragma("unroll") for (int i = 0; i < 2; i++) {                            \
      const int row = i * 64 + brow_;                                          \
      const int gs = (bslot_ ^ ((row >> 1) & 3)) * 8;                          \
      gload16(&BT[(size_t)(n0 + row) * K + (kt) + gs],                         \
              &Bs[buf][i * 2048 + t * 8]);                                     \
    }                                                                          \
  }

  // ---- prologue: tile 0 ----
  ISSUE_A(0);
  STAGE_B(0, 0);
  WRITE_A(0);
  __syncthreads();

#pragma unroll 2
  for (int tt = 0; tt < 16; tt++) {
    const int cur = tt & 1, nxt = cur ^ 1;
    if (tt < 15) {
      STAGE_B((tt + 1) * 32, nxt);  // DMA in flight across this whole iter
      ISSUE_A((tt + 1) * 32);       // reg loads covered by MFMA below
    }
    bf16x8 a[4], b[4];
#pragma unroll
    for (int mf = 0; mf < 4; mf++) {
      const int r = wm * 64 + mf * 16 + li;
      a[mf] = *reinterpret_cast<const bf16x8*>(&As[cur][r * 40 + lg * 8]);
    }
#pragma unroll
    for (int nf = 0; nf < 4; nf++) {
      const int r = wn * 64 + nf * 16 + li;
      b[nf] = *reinterpret_cast<const bf16x8*>(
          &Bs[cur][r * 32 + ((lg ^ ((r >> 1) & 3)) * 8)]);
    }
#pragma unroll
    for (int mf = 0; mf < 4; mf++)
#pragma unroll
      for (int nf = 0; nf < 4; nf++)
        acc[mf][nf] = MFMA16(a[mf], b[nf], acc[mf][nf]);
    if (tt < 15) WRITE_A(nxt);
    __syncthreads();
  }
#undef ISSUE_A
#undef WRITE_A
#undef STAGE_B

  const int lg4 = lg * 4;
#pragma unroll
  for (int nf = 0; nf < 4; nf++) {
    const int col = n0 + wn * 64 + nf * 16 + li;
    const float bv = bias[col];
#pragma unroll
    for (int mf = 0; mf < 4; mf++) {
      const int row = m0 + wm * 64 + mf * 16 + lg4;
      if constexpr (OUTF32) {
        float* o = (float*)out;
#pragma unroll
        for (int r = 0; r < 4; r++)
          o[(size_t)(row + r) * ldc + col] = acc[mf][nf][r] + bv;
      } else {
        unsigned short* o = (unsigned short*)out;
#pragma unroll
        for (int r = 0; r < 4; r++)
          o[(size_t)(row + r) * ldc + col] = f2bf_bits(acc[mf][nf][r] + bv);
      }
    }
  }
}

// Merged q + pkv + pq projections.  grid 6176 (2048 q | 4096 pkv | 32 pq).
__global__ __launch_bounds__(256, 4) void gemm2ph_qpkv(
    const float* query, const float* context, const float* pquery,
    const unsigned short* WqeT, const unsigned short* WpkveT,
    const unsigned short* WpqeT, const float* bqe, const float* bpkve,
    const float* bpqe, unsigned short* q_buf, unsigned short* pkv_buf,
    unsigned short* pq_buf) {
  const int q8 = gridDim.x >> 3;
  int wg = ((int)blockIdx.x & 7) * q8 + ((int)blockIdx.x >> 3);
  const float* A; const unsigned short* BT; const float* bias;
  unsigned short* out; int Ntiles, ldc;
  if (wg < 2048) {
    A = query; BT = WqeT; bias = bqe; out = q_buf; Ntiles = 4; ldc = 512;
  } else if (wg < 6144) {
    wg -= 2048; A = context; BT = WpkveT; bias = bpkve; out = pkv_buf;
    Ntiles = 8; ldc = 1024;
  } else {
    wg -= 6144; A = pquery; BT = WpqeT; bias = bpqe; out = pq_buf;
    Ntiles = 4; ldc = 512;
  }
  gemm2ph_body<float, 0>(A, BT, bias, out, Ntiles, ldc, wg);
}

// Final projection: attn = attn_h @ Wo + bo (bf16 A, fp32 out).  grid 2048.
__global__ __launch_bounds__(256, 4) void gemm2ph_final(
    const unsigned short* A, const unsigned short* BT, const float* bias,
    float* out) {
  const int q8 = gridDim.x >> 3;
  const int wg = ((int)blockIdx.x & 7) * q8 + ((int)blockIdx.x >> 3);
  gemm2ph_body<unsigned short, 1>(A, BT, bias, out, 4, 512, wg);
}

// ---------------------------------------------------------------------------
// 128x128 bf16 GEMM (1-phase) for the small kv/pc GEMM, N=1536 split output.
// ---------------------------------------------------------------------------
__global__ __launch_bounds__(256) void gemm_kvpc(
    const unsigned short* __restrict__ A, const unsigned short* __restrict__ BT,
    const float* __restrict__ bias0, const float* __restrict__ bias1,
    const float* __restrict__ bias2, unsigned short* out0, unsigned short* out1,
    float* out2, int Ntiles) {
  __shared__ __align__(16) unsigned short As[128 * 64];
  __shared__ __align__(16) unsigned short Bs[128 * 64];
  const int t = threadIdx.x;
  const int w = t >> 6, l = t & 63, li = l & 15, lg = l >> 4;
  const int wm = w >> 1, wn = w & 1;
  const int K = 512;
  const int m0 = (blockIdx.x / Ntiles) * 128, n0 = (blockIdx.x % Ntiles) * 128;

  f32x4 acc[4][4] = {};
  const int sr = t >> 3, sslot = t & 7;

  for (int kt = 0; kt < K; kt += 64) {
#pragma unroll
    for (int i = 0; i < 4; i++) {
      const int row = i * 32 + sr;
      const int gs = (sslot ^ (row & 7)) * 8;
      gload16(&A[(size_t)(m0 + row) * K + kt + gs], &As[(i * 256 + t) * 8]);
      gload16(&BT[(size_t)(n0 + row) * K + kt + gs], &Bs[(i * 256 + t) * 8]);
    }
    __syncthreads();
#pragma unroll
    for (int kk = 0; kk < 2; kk++) {
      bf16x8 a[4], b[4];
#pragma unroll
      for (int mf = 0; mf < 4; mf++) {
        const int r = wm * 64 + mf * 16 + li;
        a[mf] = *reinterpret_cast<const bf16x8*>(&As[r * 64 + (((kk * 4 + lg) ^ (r & 7)) * 8)]);
      }
#pragma unroll
      for (int nf = 0; nf < 4; nf++) {
        const int r = wn * 64 + nf * 16 + li;
        b[nf] = *reinterpret_cast<const bf16x8*>(&Bs[r * 64 + (((kk * 4 + lg) ^ (r & 7)) * 8)]);
      }
#pragma unroll
      for (int mf = 0; mf < 4; mf++)
#pragma unroll
        for (int nf = 0; nf < 4; nf++)
          acc[mf][nf] = MFMA16(a[mf], b[nf], acc[mf][nf]);
    }
    __syncthreads();
  }

  const int lg4 = lg * 4;
#pragma unroll
  for (int nf = 0; nf < 4; nf++) {
    const int col = n0 + wn * 64 + nf * 16 + li;
    if (col < 512) {
      const float bv = bias0[col];
#pragma unroll
      for (int mf = 0; mf < 4; mf++) {
        const int row = m0 + wm * 64 + mf * 16 + lg4;
#pragma unroll
        for (int r = 0; r < 4; r++)
          out0[(size_t)(row + r) * 512 + col] = f2bf_bits(acc[mf][nf][r] + bv);
      }
    } else if (col < 1024) {
      const float bv = bias1[col - 512];
#pragma unroll
      for (int mf = 0; mf < 4; mf++) {
        const int row = m0 + wm * 64 + mf * 16 + lg4;
#pragma unroll
        for (int r = 0; r < 4; r++)
          out1[(size_t)(row + r) * 512 + col - 512] = f2bf_bits(acc[mf][nf][r] + bv);
      }
    } else {
      const float bv = bias2[col - 1024];
#pragma unroll
      for (int mf = 0; mf < 4; mf++) {
        const int row = m0 + wm * 64 + mf * 16 + lg4;
#pragma unroll
        for (int r = 0; r < 4; r++)
          out2[(size_t)(row + r) * 512 + col - 1024] = acc[mf][nf][r] + bv;
      }
    }
  }
}

// ---------------------------------------------------------------------------
// Pack attention, split over S. grid (128 bh, 8 chunks), block 256 (4 waves).
// ---------------------------------------------------------------------------
__global__ __launch_bounds__(256) void pack_attn(
    const unsigned short* __restrict__ pq_buf,
    const unsigned short* __restrict__ pkv_buf, float* __restrict__ partial) {
  __shared__ __align__(16) unsigned short pkL[64 * 72];
  __shared__ __align__(16) unsigned short pvT[64 * 72];
  __shared__ __align__(16) unsigned short prL[4 * 16 * 72];
  const int t = threadIdx.x, w = t >> 6, l = t & 63, li = l & 15, lg = l >> 4;
  const int bh = blockIdx.x, b = bh >> 3, h = bh & 7;
  const int sb = blockIdx.y * 512;

  bf16x8 aq[2];
  {
    const size_t base = ((size_t)(b * 64 + w * 16 + li)) * 512 + h * 64;
    aq[0] = *reinterpret_cast<const bf16x8*>(&pq_buf[base + lg * 8]);
    aq[1] = *reinterpret_cast<const bf16x8*>(&pq_buf[base + 32 + lg * 8]);
  }

  f32x4 acc[4] = {};
  float lsum[4] = {};

  for (int st = 0; st < 8; st++) {
    const int s0 = sb + st * 64;
#pragma unroll
    for (int i = 0; i < 2; i++) {
      const int row = i * 32 + (t >> 3), c = (t & 7) * 8;
      const u16x8 v = *reinterpret_cast<const u16x8*>(
          &pkv_buf[((size_t)(b * 4096 + s0 + row)) * 1024 + h * 64 + c]);
      *reinterpret_cast<u16x8*>(&pkL[row * 72 + c]) = v;
    }
    {
      const int rp = t >> 3, c = (t & 7) * 8;
      const size_t base = ((size_t)(b * 4096 + s0 + 2 * rp)) * 1024 + 512 + h * 64 + c;
      const u16x8 u0 = *reinterpret_cast<const u16x8*>(&pkv_buf[base]);
      const u16x8 u1 = *reinterpret_cast<const u16x8*>(&pkv_buf[base + 1024]);
#pragma unroll
      for (int j = 0; j < 8; j++) {
        const int val = ((int)u0[j] & 0xffff) | ((int)u1[j] << 16);
        *reinterpret_cast<int*>(&pvT[(c + j) * 72 + 2 * rp]) = val;
      }
    }
    __syncthreads();
    f32x4 sc[4] = {};
#pragma unroll
    for (int nf = 0; nf < 4; nf++) {
#pragma unroll
      for (int kk = 0; kk < 2; kk++) {
        const bf16x8 bk = *reinterpret_cast<const bf16x8*>(
            &pkL[(nf * 16 + li) * 72 + kk * 32 + lg * 8]);
        sc[nf] = MFMA16(aq[kk], bk, sc[nf]);
      }
    }
#pragma unroll
    for (int nf = 0; nf < 4; nf++) {
#pragma unroll
      for (int r = 0; r < 4; r++) {
        const float e = __expf(sc[nf][r]);
        lsum[r] += e;
        prL[(w * 16 + lg * 4 + r) * 72 + nf * 16 + li] = f2bf_bits(e);
      }
    }
#pragma unroll
    for (int kk = 0; kk < 2; kk++) {
      const bf16x8 ap = *reinterpret_cast<const bf16x8*>(
          &prL[(w * 16 + li) * 72 + kk * 32 + lg * 8]);
#pragma unroll
      for (int nf = 0; nf < 4; nf++) {
        const bf16x8 bv = *reinterpret_cast<const bf16x8*>(
            &pvT[(nf * 16 + li) * 72 + kk * 32 + lg * 8]);
        acc[nf] = MFMA16(ap, bv, acc[nf]);
      }
    }
    __syncthreads();
  }

#pragma unroll
  for (int m = 1; m < 16; m <<= 1)
#pragma unroll
    for (int r = 0; r < 4; r++) lsum[r] += __shfl_xor(lsum[r], m);

  const size_t pbase = ((size_t)(bh * 8 + blockIdx.y)) * 4160;
#pragma unroll
  for (int nf = 0; nf < 4; nf++)
#pragma unroll
    for (int r = 0; r < 4; r++)
      partial[pbase + (size_t)(w * 16 + lg * 4 + r) * 64 + nf * 16 + li] = acc[nf][r];
  if (li == 0)
#pragma unroll
    for (int r = 0; r < 4; r++) partial[pbase + 4096 + w * 16 + lg * 4 + r] = lsum[r];
}

__global__ __launch_bounds__(256) void pack_combine(const float* __restrict__ partial,
                                                    unsigned short* __restrict__ pc_buf) {
  const int bh = blockIdx.x, b = bh >> 3, h = bh & 7;
  const int t = threadIdx.x;
#pragma unroll
  for (int e = 0; e < 16; e++) {
    const int idx = e * 256 + t;
    const int p = idx >> 6, d = idx & 63;
    float s = 0.f, den = 0.f;
#pragma unroll
    for (int c = 0; c < 8; c++) {
      const float* pb = &partial[((size_t)(bh * 8 + c)) * 4160];
      s += pb[idx];
      den += pb[4096 + p];
    }
    pc_buf[((size_t)(b * 64 + p)) * 512 + h * 64 + d] = f2bf_bits(s / den);
  }
}

// ---------------------------------------------------------------------------
// Unpack attention. grid (16 s-tiles, 128 bh), block 256 (4 waves x 64 s-rows).
// ---------------------------------------------------------------------------
__global__ __launch_bounds__(256) void unpack_attn(
    const unsigned short* q_in, const unsigned short* __restrict__ k_buf,
    const unsigned short* __restrict__ v_buf, float* __restrict__ aw_out,
    unsigned short* attnh_out) {
  __shared__ __align__(16) unsigned short kL[64 * 72];
  __shared__ __align__(16) unsigned short vT[64 * 72];
  __shared__ __align__(16) unsigned short prL[4 * 64 * 72];
  const int t = threadIdx.x, w = t >> 6, l = t & 63, li = l & 15, lg = l >> 4;
  const int bh = blockIdx.y, b = bh >> 3, h = bh & 7;
  const int sbase = blockIdx.x * 256 + w * 64;

#pragma unroll
  for (int i = 0; i < 2; i++) {
    const int p = i * 32 + (t >> 3), c = (t & 7) * 8;
    const u16x8 v = *reinterpret_cast<const u16x8*>(
        &k_buf[((size_t)(b * 64 + p)) * 512 + h * 64 + c]);
    *reinterpret_cast<u16x8*>(&kL[p * 72 + c]) = v;
  }
  {
    const int rp = t >> 3, c = (t & 7) * 8;
    const size_t base = ((size_t)(b * 64 + 2 * rp)) * 512 + h * 64 + c;
    const u16x8 u0 = *reinterpret_cast<const u16x8*>(&v_buf[base]);
    const u16x8 u1 = *reinterpret_cast<const u16x8*>(&v_buf[base + 512]);
#pragma unroll
    for (int j = 0; j < 8; j++) {
      const int val = ((int)u0[j] & 0xffff) | ((int)u1[j] << 16);
      *reinterpret_cast<int*>(&vT[(c + j) * 72 + 2 * rp]) = val;
    }
  }
  bf16x8 aq[4][2];
#pragma unroll
  for (int mf = 0; mf < 4; mf++) {
    const size_t base = ((size_t)(b * 4096 + sbase + mf * 16 + li)) * 512 + h * 64;
    aq[mf][0] = *reinterpret_cast<const bf16x8*>(&q_in[base + lg * 8]);
    aq[mf][1] = *reinterpret_cast<const bf16x8*>(&q_in[base + 32 + lg * 8]);
  }
  __syncthreads();

  f32x4 sc[4][4] = {};
#pragma unroll
  for (int kk = 0; kk < 2; kk++)
#pragma unroll
    for (int nf = 0; nf < 4; nf++) {
      const bf16x8 bk = *reinterpret_cast<const bf16x8*>(
          &kL[(nf * 16 + li) * 72 + kk * 32 + lg * 8]);
#pragma unroll
      for (int mf = 0; mf < 4; mf++) sc[mf][nf] = MFMA16(aq[mf][kk], bk, sc[mf][nf]);
    }

#pragma unroll
  for (int mf = 0; mf < 4; mf++) {
#pragma unroll
    for (int r = 0; r < 4; r++) {
      float e[4];
      float rs = 0.f;
#pragma unroll
      for (int nf = 0; nf < 4; nf++) {
        e[nf] = __expf(sc[mf][nf][r]);
        rs += e[nf];
      }
#pragma unroll
      for (int m = 1; m < 16; m <<= 1) rs += __shfl_xor(rs, m);
      const float inv = 1.0f / rs;
      const int srow = sbase + mf * 16 + lg * 4 + r;
#pragma unroll
      for (int nf = 0; nf < 4; nf++) {
        const float pr = e[nf] * inv;
        aw_out[(size_t)srow * 8192 + bh * 64 + nf * 16 + li] = pr;
        prL[(w * 64 + mf * 16 + lg * 4 + r) * 72 + nf * 16 + li] = f2bf_bits(pr);
      }
    }
  }

  f32x4 acc[4][4] = {};
#pragma unroll
  for (int kk = 0; kk < 2; kk++)
#pragma unroll
    for (int mf = 0; mf < 4; mf++) {
      const bf16x8 ap = *reinterpret_cast<const bf16x8*>(
          &prL[(w * 64 + mf * 16 + li) * 72 + kk * 32 + lg * 8]);
#pragma unroll
      for (int nf = 0; nf < 4; nf++) {
        const bf16x8 bv = *reinterpret_cast<const bf16x8*>(
            &vT[(nf * 16 + li) * 72 + kk * 32 + lg * 8]);
        acc[mf][nf] = MFMA16(ap, bv, acc[mf][nf]);
      }
    }
#pragma unroll
  for (int mf = 0; mf < 4; mf++)
#pragma unroll
    for (int nf = 0; nf < 4; nf++)
#pragma unroll
      for (int r = 0; r < 4; r++)
        attnh_out[((size_t)(b * 4096 + sbase + mf * 16 + lg * 4 + r)) * 512 + h * 64 +
                  nf * 16 + li] = f2bf_bits(acc[mf][nf][r]);
}

// ---------------------------------------------------------------------------
extern "C" void kernel_launch(void* const* d_in, const int* in_sizes, int n_in,
                              void* d_out, int out_size, void* d_ws, size_t ws_size,
                              hipStream_t stream) {
  (void)in_sizes; (void)n_in; (void)out_size; (void)ws_size;

  const float* query   = (const float*)d_in[0];
  const float* pquery  = (const float*)d_in[1];
  const float* context = (const float*)d_in[2];
  const float* Wi  = (const float*)d_in[3];  const float* bi  = (const float*)d_in[4];
  const float* Wip = (const float*)d_in[5];  const float* bip = (const float*)d_in[6];
  const float* Wic = (const float*)d_in[7];  const float* bic = (const float*)d_in[8];
  const float* Wq  = (const float*)d_in[9];  const float* bq  = (const float*)d_in[10];
  const float* Wpq = (const float*)d_in[11]; const float* bpq = (const float*)d_in[12];
  const float* Wk  = (const float*)d_in[13]; const float* bk  = (const float*)d_in[14];
  const float* Wpk = (const float*)d_in[15]; const float* bpk = (const float*)d_in[16];
  const float* Wv  = (const float*)d_in[17]; const float* bv  = (const float*)d_in[18];
  const float* Wpv = (const float*)d_in[19]; const float* bpv = (const float*)d_in[20];
  const float* Wo  = (const float*)d_in[21]; const float* bo  = (const float*)d_in[22];
  const float* Wop = (const float*)d_in[23]; const float* bop = (const float*)d_in[24];

  // ---- workspace layout ----
  char* ws = (char*)d_ws;
  unsigned short* WT     = (unsigned short*)(ws);                 // 8 x 512x512 bf16
  unsigned short* WqeT   = (unsigned short*)(ws + 4u * 1024 * 1024);
  unsigned short* WpqeT  = WqeT + 512 * 512;
  unsigned short* WpkveT = WpqeT + 512 * 512;                     // 1024 x 512
  float* bqe   = (float*)(WpkveT + (size_t)1024 * 512);
  float* bpqe  = bqe + 512;
  float* bpkve = bpqe + 512;
  unsigned short* q_buf   = (unsigned short*)(ws + 8u * 1024 * 1024);  // 65536x512 (later attn_h)
  unsigned short* pkv_buf = q_buf + (size_t)65536 * 512;               // 65536x1024
  unsigned short* pq_buf  = pkv_buf + (size_t)65536 * 1024;
  unsigned short* pc_buf  = pq_buf + (size_t)1024 * 512;
  unsigned short* k_buf   = pc_buf + (size_t)1024 * 512;
  unsigned short* v_buf   = k_buf + (size_t)1024 * 512;
  float* partial = (float*)(v_buf + (size_t)1024 * 512);               // 1024 x 4160 f32

  float* out_attn = (float*)d_out;                       // (B,S,512) fp32
  float* out_pc   = out_attn + (size_t)16 * 4096 * 512;  // (B,P,512)
  float* out_aw   = out_pc + (size_t)16 * 64 * 512;      // (S,B*H,P)

  const dim3 blk(256);

  // 1) weight prep
  Ptr8 tsrc; tsrc.p[0]=Wq; tsrc.p[1]=Wpq; tsrc.p[2]=Wpk; tsrc.p[3]=Wpv;
  tsrc.p[4]=Wk; tsrc.p[5]=Wv; tsrc.p[6]=Wop; tsrc.p[7]=Wo;
  prep_kernel<<<dim3(16, 16, 9), blk, 0, stream>>>(
      tsrc, WT, bi, bip, bic, Wq, Wpq, Wpk, Wpv, bq, bpq, bpk, bpv, bqe);
  gemm_wcomb<<<dim3(4, 4, 4), blk, 0, stream>>>(Wi, Wip, Wic, WT, WqeT);

  // 2) all input projections in ONE launch (q | pkv | pq)
  gemm2ph_qpkv<<<dim3(6176), blk, 0, stream>>>(
      query, context, pquery, WqeT, WpkveT, WpqeT, bqe, bpkve, bpqe,
      q_buf, pkv_buf, pq_buf);

  // 3) pack attention (8 chunks) + combine -> pc
  pack_attn<<<dim3(128, 8), blk, 0, stream>>>(pq_buf, pkv_buf, partial);
  pack_combine<<<128, blk, 0, stream>>>(partial, pc_buf);

  // 4) k, v, pc_out (fused N=1536)
  gemm_kvpc<<<dim3(96), blk, 0, stream>>>(
      pc_buf, WT + (size_t)4 * 262144, bk, bv, bop, k_buf, v_buf, out_pc, 12);

  // 5) unpack attention: aw_t out + attn_h in-place over q_buf
  unpack_attn<<<dim3(16, 128), blk, 0, stream>>>(q_buf, k_buf, v_buf, out_aw, q_buf);

  // 6) final projection: attn = attn_h @ Wo + bo (2-phase BK=32)
  gemm2ph_final<<<dim3(2048), blk, 0, stream>>>(
      q_buf, WT + (size_t)7 * 262144, bo, out_attn);
}